// Round 1
// baseline (261.278 us; speedup 1.0000x reference)
//
#include <hip/hip_runtime.h>

namespace {
constexpr int BATCH = 4;
constexpr int IN_N  = 32;
constexpr int OUT_N = 32;
constexpr int H_IN  = 28;     // input spatial
constexpr int HW    = 26;     // output spatial (28-3+1)
constexpr int NI    = 288;    // IN_N * 3 * 3
constexpr int D     = 16;
constexpr int ITERS = 7;
constexpr float INV_SCALE = 1.0f / 3.0f;   // 1/(sqrt(16) * 0.75)
constexpr float EPS = 1e-5f;

constexpr int SV_S = 20;      // sV row stride (floats): float4-aligned, conflict-free
constexpr int SR_S = 33;      // sR row stride: bank (i+o)%32, conflict-free row/col sweeps
constexpr int SQ_S = 17;      // sQw row stride: odd -> bijective banks over o
}

extern "C" __global__ __launch_bounds__(256, 2)
void capsule_fused(const float* __restrict__ input,
                   const float* __restrict__ w_current,
                   const float* __restrict__ w_next,
                   const float* __restrict__ ln_scale,
                   const float* __restrict__ ln_bias,
                   float* __restrict__ out) {
  __shared__ float sV[NI * SV_S];        // 23040 B  Vf[i][d]
  __shared__ float sR[NI * SR_S];        // 38016 B  r[i][o] (log-domain)
  __shared__ float sQw[OUT_N * SQ_S];    //  2176 B  w_next rows
  __shared__ float sScr[512];            //  2048 B  col partials (m,s) / later next_pose
  __shared__ float sLse[OUT_N];          //   128 B  pending col-lse per o

  const int t   = threadIdx.x;
  const int bid = blockIdx.x;
  const int b   = bid / (HW * HW);
  const int sp  = bid % (HW * HW);
  const int hh  = sp / HW;
  const int ww  = sp % HW;

  // stage w_next (qf) into LDS
  for (int e = t; e < OUT_N * D; e += 256)
    sQw[(e >> 4) * SQ_S + (e & 15)] = w_next[e];
  if (t < OUT_N) sLse[t] = 0.0f;

  // ---- step 1: V[i][p*4+r] = sum_q pose[p][q] * w_current[k,l,n][q][r] ----
  for (int i = t; i < NI; i += 256) {
    const int n  = i / 9;
    const int kl = i % 9;
    const int ky = kl / 3;
    const int kx = kl % 3;
    const float* px = input + (((b * IN_N + n) * H_IN + (hh + ky)) * H_IN + (ww + kx)) * D;
    float p[16], w[16];
    *(float4*)(p +  0) = *(const float4*)(px +  0);
    *(float4*)(p +  4) = *(const float4*)(px +  4);
    *(float4*)(p +  8) = *(const float4*)(px +  8);
    *(float4*)(p + 12) = *(const float4*)(px + 12);
    const float* wc = w_current + (kl * IN_N + n) * 16;
    *(float4*)(w +  0) = *(const float4*)(wc +  0);
    *(float4*)(w +  4) = *(const float4*)(wc +  4);
    *(float4*)(w +  8) = *(const float4*)(wc +  8);
    *(float4*)(w + 12) = *(const float4*)(wc + 12);
    float* sv = &sV[i * SV_S];
    #pragma unroll
    for (int pp = 0; pp < 4; ++pp) {
      #pragma unroll
      for (int rr = 0; rr < 4; ++rr) {
        sv[pp * 4 + rr] = p[pp * 4 + 0] * w[0 + rr] + p[pp * 4 + 1] * w[4 + rr]
                        + p[pp * 4 + 2] * w[8 + rr] + p[pp * 4 + 3] * w[12 + rr];
      }
    }
  }
  __syncthreads();

  // ---- step 2: dots -> sR[i][o] = (Vf[i] . qf[o]) / 3 ----
  // task tau: i = tau/8, o-group of 4 = (tau%8)*4 ; 2304 tasks / 256 threads = 9 passes
  for (int tau = t; tau < NI * 8; tau += 256) {
    const int i  = tau >> 3;
    const int og = (tau & 7) * 4;
    float vv[16];
    {
      const float4* sv4 = (const float4*)(&sV[i * SV_S]);
      *(float4*)(vv + 0)  = sv4[0];
      *(float4*)(vv + 4)  = sv4[1];
      *(float4*)(vv + 8)  = sv4[2];
      *(float4*)(vv + 12) = sv4[3];
    }
    #pragma unroll
    for (int j = 0; j < 4; ++j) {
      const float* qr = &sQw[(og + j) * SQ_S];
      float acc = 0.f;
      #pragma unroll
      for (int d = 0; d < 16; ++d) acc += vv[d] * qr[d];
      sR[i * SR_S + og + j] = acc * INV_SCALE;
    }
  }
  __syncthreads();

  // ---- step 3: Sinkhorn, 7 iters. Col-lse subtraction is folded forward. ----
  for (int it = 0; it < ITERS; ++it) {
    // row pass: logsumexp over o (32), one thread per row
    for (int i = t; i < NI; i += 256) {
      float* rp = &sR[i * SR_S];
      float row[32];
      float m = -1e30f;
      #pragma unroll
      for (int o = 0; o < 32; ++o) {
        row[o] = rp[o] - sLse[o];     // apply pending col offset
        m = fmaxf(m, row[o]);
      }
      float s = 0.f;
      #pragma unroll
      for (int o = 0; o < 32; ++o) s += __expf(row[o] - m);
      const float lse = m + __logf(s);
      #pragma unroll
      for (int o = 0; o < 32; ++o) rp[o] = row[o] - lse;
    }
    __syncthreads();

    // col partials: thread -> (o = t&31, chunk c = t>>5 of 36 rows)
    {
      const int o  = t & 31;
      const int c  = t >> 5;
      const int i0 = c * 36;
      float m = -1e30f;
      for (int i = i0; i < i0 + 36; ++i) m = fmaxf(m, sR[i * SR_S + o]);
      float s = 0.f;
      for (int i = i0; i < i0 + 36; ++i) s += __expf(sR[i * SR_S + o] - m);
      sScr[c * 32 + o] = m;
      sScr[256 + c * 32 + o] = s;
    }
    __syncthreads();

    // combine 8 partials per o -> sLse[o]
    if (t < 32) {
      float M = -1e30f;
      #pragma unroll
      for (int c = 0; c < 8; ++c) M = fmaxf(M, sScr[c * 32 + t]);
      float S = 0.f;
      #pragma unroll
      for (int c = 0; c < 8; ++c) S += sScr[256 + c * 32 + t] * __expf(sScr[c * 32 + t] - M);
      sLse[t] = M + __logf(S);
    }
    __syncthreads();
  }

  // ---- step 4: attn = exp(r - pending col lse), in place ----
  for (int e = t; e < NI * 32; e += 256) {
    const int i = e >> 5;
    const int o = e & 31;
    sR[i * SR_S + o] = __expf(sR[i * SR_S + o] - sLse[o]);
  }
  __syncthreads();

  // ---- step 5: next_pose[o][d] = sum_i attn[i][o] * Vf[i][d] ----
  // thread -> (o = t&31, d-pair d0=2*(t>>5)); sV read as float2
  {
    const int o  = t & 31;
    const int d0 = 2 * (t >> 5);
    float acc0 = 0.f, acc1 = 0.f;
    #pragma unroll 4
    for (int i = 0; i < NI; ++i) {
      const float a  = sR[i * SR_S + o];
      const float2 v = *(const float2*)(&sV[i * SV_S + d0]);
      acc0 += a * v.x;
      acc1 += a * v.y;
    }
    // sScr's sinkhorn role is over (barrier above); reuse as next_pose[32][16]
    sScr[o * 16 + d0]     = acc0;
    sScr[o * 16 + d0 + 1] = acc1;
  }
  __syncthreads();

  // ---- step 6: out[o][p*4+r] = sum_q np[o][p*4+q]*w_next[o][q*4+r]; LayerNorm over d ----
  {
    float vals[2];
    #pragma unroll
    for (int h2 = 0; h2 < 2; ++h2) {
      const int e  = t + h2 * 256;
      const int o  = e >> 4;
      const int d  = e & 15;
      const int pp = d >> 2;
      const int rr = d & 3;
      const float* np = &sScr[o * 16 + pp * 4];
      const float* qw = &sQw[o * SQ_S + rr];
      vals[h2] = np[0] * qw[0] + np[1] * qw[4] + np[2] * qw[8] + np[3] * qw[12];
    }
    // LN over the 16 d's: 16-lane-group butterfly (e=t and e=t+256 share lane layout)
    float s0 = vals[0], q0 = vals[0] * vals[0];
    float s1 = vals[1], q1 = vals[1] * vals[1];
    #pragma unroll
    for (int m = 8; m >= 1; m >>= 1) {
      s0 += __shfl_xor(s0, m, 16);
      q0 += __shfl_xor(q0, m, 16);
      s1 += __shfl_xor(s1, m, 16);
      q1 += __shfl_xor(q1, m, 16);
    }
    #pragma unroll
    for (int h2 = 0; h2 < 2; ++h2) {
      const int e = t + h2 * 256;
      const int o = e >> 4;
      const int d = e & 15;
      const float ss = h2 ? s1 : s0;
      const float qq = h2 ? q1 : q0;
      const float mu  = ss * (1.0f / 16.0f);
      const float var = qq * (1.0f / 16.0f) - mu * mu;
      const float rstd = rsqrtf(var + EPS);
      const float y = (vals[h2] - mu) * rstd * ln_scale[d] + ln_bias[d];
      out[(((b * OUT_N + o) * HW + hh) * HW + ww) * D + d] = y;
    }
  }
}

extern "C" void kernel_launch(void* const* d_in, const int* in_sizes, int n_in,
                              void* d_out, int out_size, void* d_ws, size_t ws_size,
                              hipStream_t stream) {
  const float* input     = (const float*)d_in[0];
  const float* w_current = (const float*)d_in[1];
  const float* w_next    = (const float*)d_in[2];
  const float* ln_scale  = (const float*)d_in[3];
  const float* ln_bias   = (const float*)d_in[4];
  float* outp = (float*)d_out;

  dim3 grid(BATCH * HW * HW);   // 2704 blocks, one per (b, h, w)
  dim3 block(256);
  capsule_fused<<<grid, block, 0, stream>>>(input, w_current, w_next,
                                            ln_scale, ln_bias, outp);
}

// Round 2
// 170.275 us; speedup vs baseline: 1.5344x; 1.5344x over previous
//
#include <hip/hip_runtime.h>
#include <hip/hip_fp16.h>

namespace {
constexpr int BATCH = 4;
constexpr int IN_N  = 32;
constexpr int OUT_N = 32;
constexpr int H_IN  = 28;     // input spatial
constexpr int HW    = 26;     // output spatial (28-3+1)
constexpr int NI    = 288;    // IN_N * 3 * 3
constexpr int D     = 16;
constexpr int ITERS = 7;
constexpr float INV_SCALE = 1.0f / 3.0f;   // 1/(sqrt(16) * 0.75)
constexpr float EPS = 1e-5f;

constexpr int SV_S = 20;      // sV row stride (floats): 80 B, float4-aligned
constexpr int SA_S = 17;      // sA row stride in half2 units (68 B): bank (17i+o2)%32, conflict-free row sweeps
}

extern "C" __global__ __launch_bounds__(256, 3)
void capsule_fused(const float* __restrict__ input,
                   const float* __restrict__ w_current,
                   const float* __restrict__ w_next,
                   const float* __restrict__ ln_scale,
                   const float* __restrict__ ln_bias,
                   float* __restrict__ out) {
  __shared__ float   sV[NI * SV_S];     // 23040 B  Vf[i][d] fp32
  __shared__ __half2 sA[NI * SA_S];     // 19584 B  A[i][o] = exp(r0), fp16
  __shared__ float   sQt[16 * 32];      //  2048 B  qf transposed [d][o] (stride 32: conflict-free)
  __shared__ float   sU[NI + 32];       //  1280 B  u[0..287], v at [288..319]
  __shared__ float   sScr[2048];        //  8192 B  col partials (16x32) / step-5 partials (256x8)
  // total 54,144 B -> 3 blocks/CU (<= 160KiB/3)

  const int t   = threadIdx.x;
  const int bid = blockIdx.x;
  const int b   = bid / (HW * HW);
  const int sp  = bid % (HW * HW);
  const int hh  = sp / HW;
  const int ww  = sp % HW;

  // stage w_next transposed: sQt[d*32+o] = w_next[o*16+d]  (conflict-free writes: bank=o)
  for (int e = t; e < OUT_N * D; e += 256) {
    const int d = e >> 5;
    const int o = e & 31;
    sQt[d * 32 + o] = w_next[o * 16 + d];
  }
  if (t < 32) sU[NI + t] = 1.0f;   // v init

  // ---- step 1: V[i][p*4+r] = sum_q pose[p][q] * w_current[k,l,n][q][r] ----
  for (int i = t; i < NI; i += 256) {
    const int n  = i / 9;
    const int kl = i % 9;
    const int ky = kl / 3;
    const int kx = kl % 3;
    const float* px = input + (((b * IN_N + n) * H_IN + (hh + ky)) * H_IN + (ww + kx)) * D;
    float p[16], w[16];
    *(float4*)(p +  0) = *(const float4*)(px +  0);
    *(float4*)(p +  4) = *(const float4*)(px +  4);
    *(float4*)(p +  8) = *(const float4*)(px +  8);
    *(float4*)(p + 12) = *(const float4*)(px + 12);
    const float* wc = w_current + (kl * IN_N + n) * 16;
    *(float4*)(w +  0) = *(const float4*)(wc +  0);
    *(float4*)(w +  4) = *(const float4*)(wc +  4);
    *(float4*)(w +  8) = *(const float4*)(wc +  8);
    *(float4*)(w + 12) = *(const float4*)(wc + 12);
    float* sv = &sV[i * SV_S];
    #pragma unroll
    for (int pp = 0; pp < 4; ++pp) {
      #pragma unroll
      for (int rr = 0; rr < 4; ++rr) {
        sv[pp * 4 + rr] = p[pp * 4 + 0] * w[0 + rr] + p[pp * 4 + 1] * w[4 + rr]
                        + p[pp * 4 + 2] * w[8 + rr] + p[pp * 4 + 3] * w[12 + rr];
      }
    }
  }
  __syncthreads();

  // ---- step 2: A[i][o] = exp((Vf[i].qf[o]) / 3) -> fp16. 4i x 4o per task ----
  for (int tau = t; tau < 72 * 8; tau += 256) {
    const int i0 = (tau >> 3) * 4;
    const int og = (tau & 7) * 4;
    float4 vv[4][4];
    #pragma unroll
    for (int ii = 0; ii < 4; ++ii) {
      const float4* sv4 = (const float4*)&sV[(i0 + ii) * SV_S];
      vv[ii][0] = sv4[0]; vv[ii][1] = sv4[1]; vv[ii][2] = sv4[2]; vv[ii][3] = sv4[3];
    }
    float acc[4][4] = {};   // [ii][j]
    #pragma unroll
    for (int d = 0; d < 16; ++d) {
      const float4 q = *(const float4*)&sQt[d * 32 + og];   // broadcast, conflict-free
      #pragma unroll
      for (int ii = 0; ii < 4; ++ii) {
        const float vd = ((const float*)&vv[ii][0])[d];
        acc[ii][0] += vd * q.x; acc[ii][1] += vd * q.y;
        acc[ii][2] += vd * q.z; acc[ii][3] += vd * q.w;
      }
    }
    #pragma unroll
    for (int ii = 0; ii < 4; ++ii) {
      const int i = i0 + ii;
      const __half2 h0 = __floats2half2_rn(__expf(acc[ii][0] * INV_SCALE),
                                           __expf(acc[ii][1] * INV_SCALE));
      const __half2 h1 = __floats2half2_rn(__expf(acc[ii][2] * INV_SCALE),
                                           __expf(acc[ii][3] * INV_SCALE));
      sA[i * SA_S + (og >> 1)]     = h0;
      sA[i * SA_S + (og >> 1) + 1] = h1;
    }
  }
  __syncthreads();

  // ---- step 3: linear Sinkhorn, u/v form. A never modified; no exp/log. ----
  for (int it = 0; it < ITERS; ++it) {
    // u pass: u_i = 1 / sum_o A[i][o] * v[o]   (thread-per-row)
    {
      float v[32];
      #pragma unroll
      for (int j = 0; j < 8; ++j)
        *(float4*)&v[4 * j] = *(const float4*)&sU[NI + 4 * j];
      for (int r = t; r < NI; r += 256) {
        const __half2* ar = &sA[r * SA_S];
        float s = 0.f;
        #pragma unroll
        for (int j = 0; j < 16; ++j) {
          const float2 a = __half22float2(ar[j]);
          s += a.x * v[2 * j] + a.y * v[2 * j + 1];
        }
        sU[r] = 1.0f / s;
      }
    }
    __syncthreads();
    // col partial sums: thread (o2 = t&15 [col pair], c = t>>4 [chunk of 18 rows])
    {
      const int o2   = t & 15;
      const int base = (t >> 4) * 18;
      float s0 = 0.f, s1 = 0.f;
      #pragma unroll
      for (int s = 0; s < 18; s += 2) {
        const float2 u2 = *(const float2*)&sU[base + s];
        const float2 a0 = __half22float2(sA[(base + s)     * SA_S + o2]);
        const float2 a1 = __half22float2(sA[(base + s + 1) * SA_S + o2]);
        s0 += a0.x * u2.x + a1.x * u2.y;
        s1 += a0.y * u2.x + a1.y * u2.y;
      }
      sScr[(t >> 4) * 32 + 2 * o2]     = s0;
      sScr[(t >> 4) * 32 + 2 * o2 + 1] = s1;
    }
    __syncthreads();
    if (t < 32) {
      float s = 0.f;
      #pragma unroll
      for (int c = 0; c < 16; ++c) s += sScr[c * 32 + t];
      sU[NI + t] = 1.0f / s;   // v
    }
    __syncthreads();
  }

  // ---- step 5: next_pose[o][d] = v_o * sum_i (A[i][o] u_i) Vf[i][d] ----
  // thread (o2 = t&15, dq = (t>>4)&3, quarter qh = t>>6 of 72 rows)
  {
    const int o2   = t & 15;
    const int dq   = (t >> 4) & 3;
    const int base = (t >> 6) * 72;
    float acc0[4] = {}, acc1[4] = {};
    for (int s4 = 0; s4 < 72; s4 += 4) {
      const float4 u4 = *(const float4*)&sU[base + s4];
      #pragma unroll
      for (int k = 0; k < 4; ++k) {
        const int i = base + s4 + k;
        const float2 a  = __half22float2(sA[i * SA_S + o2]);
        const float4 v4 = *(const float4*)&sV[i * SV_S + 4 * dq];
        const float  u  = ((const float*)&u4)[k];
        const float a0 = a.x * u, a1 = a.y * u;
        acc0[0] += a0 * v4.x; acc0[1] += a0 * v4.y; acc0[2] += a0 * v4.z; acc0[3] += a0 * v4.w;
        acc1[0] += a1 * v4.x; acc1[1] += a1 * v4.y; acc1[2] += a1 * v4.z; acc1[3] += a1 * v4.w;
      }
    }
    float4* p = (float4*)&sScr[t * 8];
    p[0] = make_float4(acc0[0], acc0[1], acc0[2], acc0[3]);
    p[1] = make_float4(acc1[0], acc1[1], acc1[2], acc1[3]);
  }
  __syncthreads();

  // combine quarters, apply v; np written into sA region (safe: all sA reads done)
  float* sNP = (float*)sA;   // 512 floats: np[o][d]
  if (t < 64) {
    const int o2 = t & 15;
    const int dq = t >> 4;
    float a0[4] = {}, a1[4] = {};
    #pragma unroll
    for (int qh = 0; qh < 4; ++qh) {
      const float* p = &sScr[(qh * 64 + t) * 8];
      #pragma unroll
      for (int j = 0; j < 4; ++j) { a0[j] += p[j]; a1[j] += p[4 + j]; }
    }
    const float v0 = sU[NI + 2 * o2];
    const float v1 = sU[NI + 2 * o2 + 1];
    #pragma unroll
    for (int j = 0; j < 4; ++j) {
      sNP[(2 * o2)     * 16 + 4 * dq + j] = a0[j] * v0;
      sNP[(2 * o2 + 1) * 16 + 4 * dq + j] = a1[j] * v1;
    }
  }
  __syncthreads();

  // ---- step 6: out[o][p*4+r] = sum_q np[o][p*4+q]*w_next[o][q*4+r]; LayerNorm over d ----
  {
    float vals[2];
    #pragma unroll
    for (int h2 = 0; h2 < 2; ++h2) {
      const int e  = t + h2 * 256;
      const int o  = e >> 4;
      const int d  = e & 15;
      const int pp = d >> 2;
      const int rr = d & 3;
      const float* np = &sNP[o * 16 + pp * 4];
      float acc = 0.f;
      #pragma unroll
      for (int q = 0; q < 4; ++q)
        acc += np[q] * sQt[(q * 4 + rr) * 32 + o];   // w_next[o][q*4+rr]
      vals[h2] = acc;
    }
    // LN over the 16 d's: 16-lane-group butterfly
    float s0 = vals[0], q0 = vals[0] * vals[0];
    float s1 = vals[1], q1 = vals[1] * vals[1];
    #pragma unroll
    for (int m = 8; m >= 1; m >>= 1) {
      s0 += __shfl_xor(s0, m, 16);
      q0 += __shfl_xor(q0, m, 16);
      s1 += __shfl_xor(s1, m, 16);
      q1 += __shfl_xor(q1, m, 16);
    }
    #pragma unroll
    for (int h2 = 0; h2 < 2; ++h2) {
      const int e = t + h2 * 256;
      const int o = e >> 4;
      const int d = e & 15;
      const float ss = h2 ? s1 : s0;
      const float qq = h2 ? q1 : q0;
      const float mu  = ss * (1.0f / 16.0f);
      const float var = qq * (1.0f / 16.0f) - mu * mu;
      const float rstd = rsqrtf(var + EPS);
      const float y = (vals[h2] - mu) * rstd * ln_scale[d] + ln_bias[d];
      out[(((b * OUT_N + o) * HW + hh) * HW + ww) * D + d] = y;
    }
  }
}

extern "C" void kernel_launch(void* const* d_in, const int* in_sizes, int n_in,
                              void* d_out, int out_size, void* d_ws, size_t ws_size,
                              hipStream_t stream) {
  const float* input     = (const float*)d_in[0];
  const float* w_current = (const float*)d_in[1];
  const float* w_next    = (const float*)d_in[2];
  const float* ln_scale  = (const float*)d_in[3];
  const float* ln_bias   = (const float*)d_in[4];
  float* outp = (float*)d_out;

  dim3 grid(BATCH * HW * HW);   // 2704 blocks, one per (b, h, w)
  dim3 block(256);
  capsule_fused<<<grid, block, 0, stream>>>(input, w_current, w_next,
                                            ln_scale, ln_bias, outp);
}

// Round 3
// 144.002 us; speedup vs baseline: 1.8144x; 1.1825x over previous
//
#include <hip/hip_runtime.h>
#include <hip/hip_fp16.h>

namespace {
constexpr int BATCH = 4;
constexpr int IN_N  = 32;
constexpr int OUT_N = 32;
constexpr int H_IN  = 28;     // input spatial
constexpr int HW    = 26;     // output spatial (28-3+1)
constexpr int NI    = 288;    // IN_N * 3 * 3
constexpr int D     = 16;
constexpr int ITERS = 7;
constexpr float INV_SCALE = 1.0f / 3.0f;   // 1/(sqrt(16) * 0.75)
constexpr float EPS = 1e-5f;

constexpr int SV_S = 20;      // sV row stride (floats, 80 B): b128-aligned, conflict-free
constexpr int SA_S = 20;      // sA row stride (half2, 80 B): b128/b64-aligned; all sweeps <=2-way
}

extern "C" __global__ __launch_bounds__(256, 3)
void capsule_fused(const float* __restrict__ input,
                   const float* __restrict__ w_current,
                   const float* __restrict__ w_next,
                   const float* __restrict__ ln_scale,
                   const float* __restrict__ ln_bias,
                   float* __restrict__ out) {
  __shared__ float   sV[NI * SV_S];     // 23040 B  Vf[i][d] fp32
  __shared__ __half2 sA[NI * SA_S];     // 23040 B  A[i][o] fp16; later: step-5 partials overlay
  __shared__ float   sQt[16 * 32];      //  2048 B  qf transposed [d][o]
  __shared__ float   sU[NI + 32];       //  1280 B  u[0..287], v at [288..319]
  __shared__ float   sScr[512];         //  2048 B  sinkhorn col partials / final np[32][16]
  // total 51,456 B -> 3 blocks/CU

  const int t   = threadIdx.x;
  const int bid = blockIdx.x;
  const int b   = bid / (HW * HW);
  const int sp  = bid % (HW * HW);
  const int hh  = sp / HW;
  const int ww  = sp % HW;

  // stage w_next transposed: sQt[d*32+o] = w_next[o*16+d]
  for (int e = t; e < OUT_N * D; e += 256) {
    const int d = e >> 5;
    const int o = e & 31;
    sQt[d * 32 + o] = w_next[o * 16 + d];
  }
  if (t < 32) sU[NI + t] = 1.0f;   // v init

  // ---- step 1: V[i][p*4+r] = sum_q pose[p][q] * w_current[k,l,n][q][r] ----
  for (int i = t; i < NI; i += 256) {
    const int n  = i / 9;
    const int kl = i % 9;
    const int ky = kl / 3;
    const int kx = kl % 3;
    const float* px = input + (((b * IN_N + n) * H_IN + (hh + ky)) * H_IN + (ww + kx)) * D;
    float p[16], w[16];
    *(float4*)(p +  0) = *(const float4*)(px +  0);
    *(float4*)(p +  4) = *(const float4*)(px +  4);
    *(float4*)(p +  8) = *(const float4*)(px +  8);
    *(float4*)(p + 12) = *(const float4*)(px + 12);
    const float* wc = w_current + (kl * IN_N + n) * 16;
    *(float4*)(w +  0) = *(const float4*)(wc +  0);
    *(float4*)(w +  4) = *(const float4*)(wc +  4);
    *(float4*)(w +  8) = *(const float4*)(wc +  8);
    *(float4*)(w + 12) = *(const float4*)(wc + 12);
    float* sv = &sV[i * SV_S];
    #pragma unroll
    for (int pp = 0; pp < 4; ++pp) {
      #pragma unroll
      for (int rr = 0; rr < 4; ++rr) {
        sv[pp * 4 + rr] = p[pp * 4 + 0] * w[0 + rr] + p[pp * 4 + 1] * w[4 + rr]
                        + p[pp * 4 + 2] * w[8 + rr] + p[pp * 4 + 3] * w[12 + rr];
      }
    }
  }
  __syncthreads();

  // ---- step 2: A[r][o] = exp((Vf[r].qf[o])/3) -> fp16 ----
  // thread: og = (t&7)*4 fixed across passes (q block hoisted); row r = (t>>3)+32p
  {
    const int og = (t & 7) * 4;
    float4 q0[16];
    #pragma unroll
    for (int d = 0; d < 16; ++d) q0[d] = *(const float4*)&sQt[d * 32 + og];
    #pragma unroll
    for (int p = 0; p < 9; ++p) {
      const int r = (t >> 3) + 32 * p;
      float vrow[16];
      const float4* sv4 = (const float4*)&sV[r * SV_S];
      *(float4*)(vrow +  0) = sv4[0];
      *(float4*)(vrow +  4) = sv4[1];
      *(float4*)(vrow +  8) = sv4[2];
      *(float4*)(vrow + 12) = sv4[3];
      float a0 = 0.f, a1 = 0.f, a2 = 0.f, a3 = 0.f;
      #pragma unroll
      for (int d = 0; d < 16; ++d) {
        const float vd = vrow[d];
        a0 += vd * q0[d].x; a1 += vd * q0[d].y;
        a2 += vd * q0[d].z; a3 += vd * q0[d].w;
      }
      union { __half2 h[2]; uint2 u; } pk;
      pk.h[0] = __floats2half2_rn(__expf(a0 * INV_SCALE), __expf(a1 * INV_SCALE));
      pk.h[1] = __floats2half2_rn(__expf(a2 * INV_SCALE), __expf(a3 * INV_SCALE));
      *(uint2*)&sA[r * SA_S + (og >> 1)] = pk.u;
    }
  }
  __syncthreads();

  // ---- step 3: linear Sinkhorn, u/v form. A never modified; no exp/log. ----
  for (int it = 0; it < ITERS; ++it) {
    // u pass: u_i = 1 / sum_o A[i][o] * v[o]
    {
      float v[32];
      #pragma unroll
      for (int j = 0; j < 8; ++j)
        *(float4*)&v[4 * j] = *(const float4*)&sU[NI + 4 * j];
      for (int r = t; r < NI; r += 256) {
        const __half2* ar = &sA[r * SA_S];
        float s = 0.f;
        #pragma unroll
        for (int j = 0; j < 16; ++j) {
          const float2 a = __half22float2(ar[j]);
          s += a.x * v[2 * j] + a.y * v[2 * j + 1];
        }
        sU[r] = 1.0f / s;
      }
    }
    __syncthreads();
    // col partial sums: thread (o2 = t&15 [col pair], c = t>>4 [chunk of 18 rows])
    {
      const int o2   = t & 15;
      const int base = (t >> 4) * 18;
      float s0 = 0.f, s1 = 0.f;
      #pragma unroll
      for (int s = 0; s < 18; s += 2) {
        const float2 u2 = *(const float2*)&sU[base + s];
        const float2 a0 = __half22float2(sA[(base + s)     * SA_S + o2]);
        const float2 a1 = __half22float2(sA[(base + s + 1) * SA_S + o2]);
        s0 += a0.x * u2.x + a1.x * u2.y;
        s1 += a0.y * u2.x + a1.y * u2.y;
      }
      sScr[(t >> 4) * 32 + 2 * o2]     = s0;
      sScr[(t >> 4) * 32 + 2 * o2 + 1] = s1;
    }
    __syncthreads();
    if (t < 32) {
      float s = 0.f;
      #pragma unroll
      for (int c = 0; c < 16; ++c) s += sScr[c * 32 + t];
      sU[NI + t] = 1.0f / s;   // v
    }
    __syncthreads();
  }

  // ---- step 5: next_pose[o][d] = v_o * sum_i (A[i][o] u_i) Vf[i][d] ----
  // wave w owns rows [72w,72w+72); lane: ro = l>>5 (row parity), g = (l&31)&7 (o-quad),
  // dq = (l&31)>>3 (d-quad). 2-row in-wave split, shfl_xor(32) reduce.
  {
    const int w    = t >> 6;
    const int l    = t & 63;
    const int ro   = l >> 5;
    const int rem  = l & 31;
    const int g    = rem & 7;
    const int dq   = rem >> 3;
    const int base = w * 72;
    float acc[4][4] = {};
    for (int s = 0; s < 36; ++s) {
      const int i = base + 2 * s + ro;
      const float u = sU[i];
      const uint2 araw = *(const uint2*)&sA[i * SA_S + 2 * g];   // A[i][4g..4g+3]
      const float2 f01 = __half22float2(((const __half2*)&araw)[0]);
      const float2 f23 = __half22float2(((const __half2*)&araw)[1]);
      const float4 v4  = *(const float4*)&sV[i * SV_S + 4 * dq];
      const float au0 = f01.x * u, au1 = f01.y * u, au2 = f23.x * u, au3 = f23.y * u;
      acc[0][0] += au0 * v4.x; acc[0][1] += au0 * v4.y; acc[0][2] += au0 * v4.z; acc[0][3] += au0 * v4.w;
      acc[1][0] += au1 * v4.x; acc[1][1] += au1 * v4.y; acc[1][2] += au1 * v4.z; acc[1][3] += au1 * v4.w;
      acc[2][0] += au2 * v4.x; acc[2][1] += au2 * v4.y; acc[2][2] += au2 * v4.z; acc[2][3] += au2 * v4.w;
      acc[3][0] += au3 * v4.x; acc[3][1] += au3 * v4.y; acc[3][2] += au3 * v4.z; acc[3][3] += au3 * v4.w;
    }
    #pragma unroll
    for (int a = 0; a < 4; ++a)
      #pragma unroll
      for (int bb = 0; bb < 4; ++bb)
        acc[a][bb] += __shfl_xor(acc[a][bb], 32);

    __syncthreads();               // all sA reads complete before overlay
    float* P = (float*)sA;         // partials overlay: record stride 20 floats
    if (l < 32) {
      float* p = P + (w * 32 + l) * 20;
      *(float4*)(p +  0) = make_float4(acc[0][0], acc[0][1], acc[0][2], acc[0][3]);
      *(float4*)(p +  4) = make_float4(acc[1][0], acc[1][1], acc[1][2], acc[1][3]);
      *(float4*)(p +  8) = make_float4(acc[2][0], acc[2][1], acc[2][2], acc[2][3]);
      *(float4*)(p + 12) = make_float4(acc[3][0], acc[3][1], acc[3][2], acc[3][3]);
    }
    __syncthreads();
    // combine quarters, apply v; np -> sScr[o*16+d] (sinkhorn use of sScr is over)
    if (t < 128) {
      const int l2  = t & 31;
      const int a   = t >> 5;      // o-offset within quad
      const int g2  = l2 & 7;
      const int dq2 = l2 >> 3;
      float4 r = make_float4(0.f, 0.f, 0.f, 0.f);
      #pragma unroll
      for (int q = 0; q < 4; ++q) {
        const float4 pv = *(const float4*)(P + (q * 32 + l2) * 20 + 4 * a);
        r.x += pv.x; r.y += pv.y; r.z += pv.z; r.w += pv.w;
      }
      const int o = 4 * g2 + a;
      const float vo = sU[NI + o];
      *(float4*)&sScr[o * 16 + 4 * dq2] = make_float4(r.x * vo, r.y * vo, r.z * vo, r.w * vo);
    }
  }
  __syncthreads();

  // ---- step 6: out[o][p*4+r] = sum_q np[o][p*4+q]*w_next[o][q*4+r]; LayerNorm over d ----
  {
    float vals[2];
    #pragma unroll
    for (int h2 = 0; h2 < 2; ++h2) {
      const int e  = t + h2 * 256;
      const int o  = e >> 4;
      const int d  = e & 15;
      const int pp = d >> 2;
      const int rr = d & 3;
      const float* np = &sScr[o * 16 + pp * 4];
      float acc = 0.f;
      #pragma unroll
      for (int q = 0; q < 4; ++q)
        acc += np[q] * sQt[(q * 4 + rr) * 32 + o];   // w_next[o][q*4+rr]
      vals[h2] = acc;
    }
    float s0 = vals[0], q0 = vals[0] * vals[0];
    float s1 = vals[1], q1 = vals[1] * vals[1];
    #pragma unroll
    for (int m = 8; m >= 1; m >>= 1) {
      s0 += __shfl_xor(s0, m, 16);
      q0 += __shfl_xor(q0, m, 16);
      s1 += __shfl_xor(s1, m, 16);
      q1 += __shfl_xor(q1, m, 16);
    }
    #pragma unroll
    for (int h2 = 0; h2 < 2; ++h2) {
      const int e = t + h2 * 256;
      const int o = e >> 4;
      const int d = e & 15;
      const float ss = h2 ? s1 : s0;
      const float qq = h2 ? q1 : q0;
      const float mu  = ss * (1.0f / 16.0f);
      const float var = qq * (1.0f / 16.0f) - mu * mu;
      const float rstd = rsqrtf(var + EPS);
      const float y = (vals[h2] - mu) * rstd * ln_scale[d] + ln_bias[d];
      out[(((b * OUT_N + o) * HW + hh) * HW + ww) * D + d] = y;
    }
  }
}

extern "C" void kernel_launch(void* const* d_in, const int* in_sizes, int n_in,
                              void* d_out, int out_size, void* d_ws, size_t ws_size,
                              hipStream_t stream) {
  const float* input     = (const float*)d_in[0];
  const float* w_current = (const float*)d_in[1];
  const float* w_next    = (const float*)d_in[2];
  const float* ln_scale  = (const float*)d_in[3];
  const float* ln_bias   = (const float*)d_in[4];
  float* outp = (float*)d_out;

  dim3 grid(BATCH * HW * HW);   // 2704 blocks, one per (b, h, w)
  dim3 block(256);
  capsule_fused<<<grid, block, 0, stream>>>(input, w_current, w_next,
                                            ln_scale, ln_bias, outp);
}

// Round 6
// 121.361 us; speedup vs baseline: 2.1529x; 1.1866x over previous
//
#include <hip/hip_runtime.h>

typedef _Float16 h2 __attribute__((ext_vector_type(2)));
typedef _Float16 h8 __attribute__((ext_vector_type(8)));
typedef __fp16   g2 __attribute__((ext_vector_type(2)));
typedef float    v4f __attribute__((ext_vector_type(4)));

namespace {
constexpr int BATCH = 4;
constexpr int IN_N  = 32;
constexpr int OUT_N = 32;
constexpr int H_IN  = 28;     // input spatial
constexpr int HW    = 26;     // output spatial (28-3+1)
constexpr int NI    = 288;    // IN_N * 3 * 3
constexpr int D     = 16;
constexpr int ITERS = 7;
constexpr float INV_SCALE = 1.0f / 3.0f;   // 1/(sqrt(16) * 0.75)
constexpr float EPS = 1e-5f;

constexpr int VH_S = 24;      // sVh row stride (halves, 48 B): b128 row reads conflict-free
constexpr int AT_S = 296;     // sAt row stride (halves, 592 B): 16B-aligned b128 rows
constexpr int P_S  = 36;      // step-5 partial stride (floats)
}

union H8U { h2 q[4]; h8 v; int2 i2[2]; };

static __device__ __forceinline__ int h2bits(h2 x) { union { h2 h; int i; } u; u.h = x; return u.i; }

// cvt_pkrtz returns __fp16x2; bit-cast to our _Float16-based h2
static __device__ __forceinline__ h2 pkrtz(float a, float b) {
  union { g2 g; h2 h; } u;
  u.g = __builtin_amdgcn_cvt_pkrtz(a, b);
  return u.h;
}

static __device__ __forceinline__ float dot2f(h2 a, h2 b, float c) {
#if __has_builtin(__builtin_amdgcn_fdot2)
  return __builtin_amdgcn_fdot2(a, b, c, false);
#else
  return c + (float)a.x * (float)b.x + (float)a.y * (float)b.y;
#endif
}

extern "C" __global__ __launch_bounds__(256, 4)
void capsule_fused(const float* __restrict__ input,
                   const float* __restrict__ w_current,
                   const float* __restrict__ w_next,
                   const float* __restrict__ ln_scale,
                   const float* __restrict__ ln_bias,
                   float* __restrict__ out) {
  // Manual LDS carving: 38144 B total -> 4 blocks/CU.
  __shared__ __align__(16) unsigned char smem[38144];
  _Float16* sVh  = (_Float16*)(smem);            // [288][24] halves (13824 B)
  float*    Pf   = (float*)(smem);               // overlay: step-5 partials [4][16][36] (9216 B)
  _Float16* sAt  = (_Float16*)(smem + 13824);    // A^T [32][296] halves (18944 B)
  float*    sQt  = (float*)(smem + 32768);       // qf^T [16][32] * INV_SCALE (2048 B)
  float*    sU   = (float*)(smem + 34816);       // u[0..287], v[288..319] (1280 B)
  float*    sScr = (float*)(smem + 36096);       // sinkhorn col partials / np[16][32] (2048 B)

  const int t   = threadIdx.x;
  const int l   = t & 63;
  const int wv  = t >> 6;
  const int bid = blockIdx.x;
  const int b   = bid / (HW * HW);
  const int sp  = bid % (HW * HW);
  const int hh  = sp / HW;
  const int ww  = sp % HW;

  H8U zu; zu.i2[0] = make_int2(0, 0); zu.i2[1] = make_int2(0, 0);
  const h8 zero8 = zu.v;

  // stage qf^T scaled: sQt[d][o] = w_next[o][d] / 3
  for (int e = t; e < OUT_N * D; e += 256) {
    const int d = e >> 5, o = e & 31;
    sQt[d * 32 + o] = w_next[o * 16 + d] * INV_SCALE;
  }
  if (t < 32) sU[NI + t] = 1.0f;   // v init

  // ---- step 1: V[i][p*4+r] = sum_q pose[p][q]*w_current[q][r]; store f16 ----
  for (int i = t; i < NI; i += 256) {
    const int n = i / 9, kl = i % 9, ky = kl / 3, kx = kl % 3;
    const float* px = input + (((b * IN_N + n) * H_IN + (hh + ky)) * H_IN + (ww + kx)) * D;
    float p[16], wt[16];
    *(float4*)(p +  0) = *(const float4*)(px +  0);
    *(float4*)(p +  4) = *(const float4*)(px +  4);
    *(float4*)(p +  8) = *(const float4*)(px +  8);
    *(float4*)(p + 12) = *(const float4*)(px + 12);
    const float* wc = w_current + (kl * IN_N + n) * 16;
    *(float4*)(wt +  0) = *(const float4*)(wc +  0);
    *(float4*)(wt +  4) = *(const float4*)(wc +  4);
    *(float4*)(wt +  8) = *(const float4*)(wc +  8);
    *(float4*)(wt + 12) = *(const float4*)(wc + 12);
    float vv[16];
    #pragma unroll
    for (int pp = 0; pp < 4; ++pp)
      #pragma unroll
      for (int rr = 0; rr < 4; ++rr)
        vv[pp * 4 + rr] = p[pp*4+0]*wt[0+rr] + p[pp*4+1]*wt[4+rr]
                        + p[pp*4+2]*wt[8+rr] + p[pp*4+3]*wt[12+rr];
    H8U lo, hi;
    #pragma unroll
    for (int jj = 0; jj < 4; ++jj) {
      lo.q[jj] = pkrtz(vv[2*jj],     vv[2*jj + 1]);
      hi.q[jj] = pkrtz(vv[8 + 2*jj], vv[8 + 2*jj + 1]);
    }
    *(h8*)(sVh + i * VH_S)     = lo.v;
    *(h8*)(sVh + i * VH_S + 8) = hi.v;
  }
  __syncthreads();

  // ---- step 2: A^T[o][i] = exp(Vf[i].qf[o]/3) via MFMA 16x16x32 (K zero-padded) ----
  {
    const int lo16 = l & 15;
    const int q4   = l >> 4;          // k-quad
    const int kq   = (q4 & 1) * 8;    // real k base for quads 0,1
    const bool hiK = (q4 >= 2);       // quads 2,3 = zero-pad region (k>=16)
    h8 bf[2];
    #pragma unroll
    for (int nt = 0; nt < 2; ++nt) {
      const int o = lo16 + 16 * nt;
      H8U bu;
      #pragma unroll
      for (int jj = 0; jj < 4; ++jj)
        bu.q[jj] = pkrtz(sQt[(kq + 2*jj) * 32 + o], sQt[(kq + 2*jj + 1) * 32 + o]);
      bf[nt] = hiK ? zero8 : bu.v;
    }
    for (int mt = wv; mt < 18; mt += 4) {
      const int m = mt * 16 + lo16;
      h8 af = *(const h8*)(sVh + m * VH_S + kq);
      if (hiK) af = zero8;
      #pragma unroll
      for (int nt = 0; nt < 2; ++nt) {
        v4f acc = {0.f, 0.f, 0.f, 0.f};
        acc = __builtin_amdgcn_mfma_f32_16x16x32_f16(af, bf[nt], acc, 0, 0, 0);
        // D: col(o-within-tile)=l&15, row(i-offset)=4*q4+reg
        const int o  = lo16 + 16 * nt;
        const int ib = mt * 16 + 4 * q4;
        h2 p0 = pkrtz(__expf(acc[0]), __expf(acc[1]));
        h2 p1 = pkrtz(__expf(acc[2]), __expf(acc[3]));
        int2 wr; wr.x = h2bits(p0); wr.y = h2bits(p1);
        *(int2*)(sAt + o * AT_S + ib) = wr;   // A^T[o][ib..ib+3]
      }
    }
  }
  __syncthreads();

  // ---- step 3: Sinkhorn in registers, RESCALED: v-step uses 8/colsum so u,v stay O(1).
  // Exact compensation: attn = u~ A v~ / 8, folded into the final combine (x0.375).
  const int c4 = t & 7;
  const int hq = t >> 3;
  h2 A2a[9], A2b[9];
  {
    const _Float16* r0 = sAt + (4*c4 + 0) * AT_S + 9 * hq;
    const _Float16* r1 = sAt + (4*c4 + 1) * AT_S + 9 * hq;
    const _Float16* r2 = sAt + (4*c4 + 2) * AT_S + 9 * hq;
    const _Float16* r3 = sAt + (4*c4 + 3) * AT_S + 9 * hq;
    #pragma unroll
    for (int j = 0; j < 9; ++j) {
      h2 a; a.x = r0[j]; a.y = r1[j]; A2a[j] = a;
      h2 c; c.x = r2[j]; c.y = r3[j]; A2b[j] = c;
    }
  }
  float ureg[9];
  for (int it = 0; it < ITERS; ++it) {
    const v4f vvv = *(const v4f*)(sU + NI + 4 * c4);
    const h2 v2a = pkrtz(vvv[0], vvv[1]);
    const h2 v2b = pkrtz(vvv[2], vvv[3]);
    // u-pass: row sums over o (fp32 accum via fdot2, 8-lane butterfly over c4)
    #pragma unroll
    for (int j = 0; j < 9; ++j) {
      float s = dot2f(A2b[j], v2b, dot2f(A2a[j], v2a, 0.f));
      s += __shfl_xor(s, 1);
      s += __shfl_xor(s, 2);
      s += __shfl_xor(s, 4);
      ureg[j] = __builtin_amdgcn_rcpf(s);
    }
    // col-pass: fp32 partial col sums, butterfly over hq-in-wave, then LDS combine
    float sca = 0.f, scb = 0.f, scc = 0.f, scd = 0.f;
    #pragma unroll
    for (int j = 0; j < 9; ++j) {
      const float uj = ureg[j];
      sca += (float)A2a[j].x * uj;
      scb += (float)A2a[j].y * uj;
      scc += (float)A2b[j].x * uj;
      scd += (float)A2b[j].y * uj;
    }
    #pragma unroll
    for (int m = 8; m <= 32; m <<= 1) {
      sca += __shfl_xor(sca, m);
      scb += __shfl_xor(scb, m);
      scc += __shfl_xor(scc, m);
      scd += __shfl_xor(scd, m);
    }
    if (l < 8) {
      v4f w4; w4[0] = sca; w4[1] = scb; w4[2] = scc; w4[3] = scd;
      *(v4f*)(sScr + wv * 32 + l * 4) = w4;   // [wave][o]
    }
    __syncthreads();
    if (t < 32) {
      const float S = sScr[t] + sScr[32 + t] + sScr[64 + t] + sScr[96 + t];
      sU[NI + t] = 8.0f * __builtin_amdgcn_rcpf(S);   // rescaled v
    }
    __syncthreads();
  }
  if (c4 == 0) {
    #pragma unroll
    for (int j = 0; j < 9; ++j) sU[9 * hq + j] = ureg[j];
  }
  __syncthreads();

  // ---- step 5: np~[o][d] = sum_k A^T[o][k] * (u_k * V[k][d]) via MFMA 16x16x32 ----
  v4f acc5_0 = {0.f, 0.f, 0.f, 0.f};
  v4f acc5_1 = {0.f, 0.f, 0.f, 0.f};
  {
    const int d  = l & 15;
    const int q4 = l >> 4;
    for (int kt = wv; kt < 9; kt += 4) {
      const int kg = kt * 32 + q4 * 8;
      const v4f ua = *(const v4f*)(sU + kg);
      const v4f ub = *(const v4f*)(sU + kg + 4);
      float uu[8];
      #pragma unroll
      for (int z = 0; z < 4; ++z) { uu[z] = ua[z]; uu[4 + z] = ub[z]; }
      H8U bu;
      #pragma unroll
      for (int jj = 0; jj < 4; ++jj) {
        const float b0 = (float)sVh[(kg + 2*jj)     * VH_S + d] * uu[2*jj];
        const float b1 = (float)sVh[(kg + 2*jj + 1) * VH_S + d] * uu[2*jj + 1];
        bu.q[jj] = pkrtz(b0, b1);
      }
      const h8 af0 = *(const h8*)(sAt + d * AT_S        + kt * 32 + q4 * 8);
      const h8 af1 = *(const h8*)(sAt + (16 + d) * AT_S + kt * 32 + q4 * 8);
      acc5_0 = __builtin_amdgcn_mfma_f32_16x16x32_f16(af0, bu.v, acc5_0, 0, 0, 0);
      acc5_1 = __builtin_amdgcn_mfma_f32_16x16x32_f16(af1, bu.v, acc5_1, 0, 0, 0);
    }
  }
  __syncthreads();   // all sVh/sAt reads done -> safe to overlay P into sVh
  {
    const int d = l & 15, q4 = l >> 4;
    // D: col=d, row(o-offset)=4*q4+reg
    *(v4f*)(Pf + (wv * 16 + d) * P_S + 0  + 4 * q4) = acc5_0;
    *(v4f*)(Pf + (wv * 16 + d) * P_S + 16 + 4 * q4) = acc5_1;
  }
  __syncthreads();
  // combine K-partials; np*3 = S~ * v~_o * (3/8)  (the /8 undoes the v rescale)
  #pragma unroll
  for (int pass = 0; pass < 2; ++pass) {
    const int e = t + 256 * pass;
    const int o = e & 31, dd = e >> 5;
    const float S = Pf[(0 * 16 + dd) * P_S + o] + Pf[(1 * 16 + dd) * P_S + o]
                  + Pf[(2 * 16 + dd) * P_S + o] + Pf[(3 * 16 + dd) * P_S + o];
    sScr[dd * 32 + o] = S * 0.375f * sU[NI + o];
  }
  __syncthreads();

  // ---- step 6: out[o][p*4+r] = sum_q np[o][p*4+q]*w_next[o][q*4+r]; LayerNorm over d ----
  {
    float vals[2];
    #pragma unroll
    for (int h2p = 0; h2p < 2; ++h2p) {
      const int e = t + h2p * 256;
      const int o = e >> 4, dd = e & 15;
      const int pp = dd >> 2, rr = dd & 3;
      float acc = 0.f;
      #pragma unroll
      for (int q = 0; q < 4; ++q)
        acc += sScr[(pp * 4 + q) * 32 + o] * sQt[(q * 4 + rr) * 32 + o];
      vals[h2p] = acc;
    }
    float s0 = vals[0], q0 = vals[0] * vals[0];
    float s1 = vals[1], q1 = vals[1] * vals[1];
    #pragma unroll
    for (int m = 8; m >= 1; m >>= 1) {
      s0 += __shfl_xor(s0, m, 16);
      q0 += __shfl_xor(q0, m, 16);
      s1 += __shfl_xor(s1, m, 16);
      q1 += __shfl_xor(q1, m, 16);
    }
    #pragma unroll
    for (int h2p = 0; h2p < 2; ++h2p) {
      const int e = t + h2p * 256;
      const int o = e >> 4, dd = e & 15;
      const float ss = h2p ? s1 : s0;
      const float qq = h2p ? q1 : q0;
      const float mu   = ss * (1.0f / 16.0f);
      const float var  = qq * (1.0f / 16.0f) - mu * mu;
      const float rstd = rsqrtf(var + EPS);
      const float y = (vals[h2p] - mu) * rstd * ln_scale[dd] + ln_bias[dd];
      out[(((b * OUT_N + o) * HW + hh) * HW + ww) * D + dd] = y;
    }
  }
}

extern "C" void kernel_launch(void* const* d_in, const int* in_sizes, int n_in,
                              void* d_out, int out_size, void* d_ws, size_t ws_size,
                              hipStream_t stream) {
  const float* input     = (const float*)d_in[0];
  const float* w_current = (const float*)d_in[1];
  const float* w_next    = (const float*)d_in[2];
  const float* ln_scale  = (const float*)d_in[3];
  const float* ln_bias   = (const float*)d_in[4];
  float* outp = (float*)d_out;

  dim3 grid(BATCH * HW * HW);   // 2704 blocks, one per (b, h, w)
  dim3 block(256);
  capsule_fused<<<grid, block, 0, stream>>>(input, w_current, w_next,
                                            ln_scale, ln_bias, outp);
}

// Round 7
// 107.016 us; speedup vs baseline: 2.4415x; 1.1340x over previous
//
#include <hip/hip_runtime.h>

typedef _Float16 h2 __attribute__((ext_vector_type(2)));
typedef _Float16 h8 __attribute__((ext_vector_type(8)));
typedef __fp16   g2 __attribute__((ext_vector_type(2)));
typedef float    v4f __attribute__((ext_vector_type(4)));

namespace {
constexpr int BATCH = 4;
constexpr int IN_N  = 32;
constexpr int OUT_N = 32;
constexpr int H_IN  = 28;     // input spatial
constexpr int HW    = 26;     // output spatial (28-3+1)
constexpr int NI    = 288;    // IN_N * 3 * 3
constexpr int D     = 16;
constexpr int ITERS = 7;
constexpr float INV_SCALE = 1.0f / 3.0f;   // 1/(sqrt(16) * 0.75)
constexpr float EPS = 1e-5f;

constexpr int VH_S = 24;      // sVh row stride (halves, 48 B): b128 row reads conflict-free
constexpr int AT_S = 296;     // sAt row stride (halves, 592 B): 16B-aligned b128 rows
constexpr int P_S  = 36;      // step-5 partial stride (floats)

// DPP ctrl encodings
constexpr int DPP_XOR1 = 0xB1;   // quad_perm [1,0,3,2]
constexpr int DPP_XOR2 = 0x4E;   // quad_perm [2,3,0,1]
constexpr int DPP_HMIR = 0x141;  // row_half_mirror (xor-ish swap across 4-lane halves of 8)
constexpr int DPP_ROR4 = 0x124;  // row rotate 4 (within 16)
constexpr int DPP_ROR8 = 0x128;  // row rotate 8 == xor8 within 16
}

union H8U { h2 q[4]; h8 v; int2 i2[2]; };

static __device__ __forceinline__ int h2bits(h2 x) { union { h2 h; int i; } u; u.h = x; return u.i; }

// cvt_pkrtz returns __fp16x2; bit-cast to our _Float16-based h2
static __device__ __forceinline__ h2 pkrtz(float a, float b) {
  union { g2 g; h2 h; } u;
  u.g = __builtin_amdgcn_cvt_pkrtz(a, b);
  return u.h;
}

static __device__ __forceinline__ float dot2f(h2 a, h2 b, float c) {
#if __has_builtin(__builtin_amdgcn_fdot2)
  return __builtin_amdgcn_fdot2(a, b, c, false);
#else
  return c + (float)a.x * (float)b.x + (float)a.y * (float)b.y;
#endif
}

// x + dpp_perm(x): cross-lane add on the VALU pipe (no ds_bpermute)
template <int CTRL>
static __device__ __forceinline__ float dpp_add(float x) {
  union { float f; int i; } s, r;
  s.f = x;
  r.i = __builtin_amdgcn_update_dpp(s.i, s.i, CTRL, 0xF, 0xF, false);
  return x + r.f;
}

extern "C" __global__ __launch_bounds__(256, 4)
void capsule_fused(const float* __restrict__ input,
                   const float* __restrict__ w_current,
                   const float* __restrict__ w_next,
                   const float* __restrict__ ln_scale,
                   const float* __restrict__ ln_bias,
                   float* __restrict__ out) {
  // Manual LDS carving: 38144 B total -> 4 blocks/CU.
  __shared__ __align__(16) unsigned char smem[38144];
  _Float16* sVh  = (_Float16*)(smem);            // [288][24] halves (13824 B)
  float*    Pf   = (float*)(smem);               // overlay: step-5 partials [4][16][36] (9216 B)
  _Float16* sAt  = (_Float16*)(smem + 13824);    // A^T [32][296] halves (18944 B)
  float*    sQt  = (float*)(smem + 32768);       // qf^T [16][32] * INV_SCALE (2048 B)
  float*    sU   = (float*)(smem + 34816);       // u[0..287], v[288..319] (1280 B)
  float*    sScr = (float*)(smem + 36096);       // sinkhorn col partials [16][32] / np (2048 B)

  const int t   = threadIdx.x;
  const int l   = t & 63;
  const int wv  = t >> 6;
  const int bid = blockIdx.x;
  const int b   = bid / (HW * HW);
  const int sp  = bid % (HW * HW);
  const int hh  = sp / HW;
  const int ww  = sp % HW;

  H8U zu; zu.i2[0] = make_int2(0, 0); zu.i2[1] = make_int2(0, 0);
  const h8 zero8 = zu.v;

  // stage qf^T scaled: sQt[d][o] = w_next[o][d] / 3
  for (int e = t; e < OUT_N * D; e += 256) {
    const int d = e >> 5, o = e & 31;
    sQt[d * 32 + o] = w_next[o * 16 + d] * INV_SCALE;
  }
  if (t < 32) sU[NI + t] = 1.0f;   // v init

  // ---- step 1: V[i][p*4+r] = sum_q pose[p][q]*w_current[q][r]; store f16 ----
  for (int i = t; i < NI; i += 256) {
    const int n = i / 9, kl = i % 9, ky = kl / 3, kx = kl % 3;
    const float* px = input + (((b * IN_N + n) * H_IN + (hh + ky)) * H_IN + (ww + kx)) * D;
    float p[16], wt[16];
    *(float4*)(p +  0) = *(const float4*)(px +  0);
    *(float4*)(p +  4) = *(const float4*)(px +  4);
    *(float4*)(p +  8) = *(const float4*)(px +  8);
    *(float4*)(p + 12) = *(const float4*)(px + 12);
    const float* wc = w_current + (kl * IN_N + n) * 16;
    *(float4*)(wt +  0) = *(const float4*)(wc +  0);
    *(float4*)(wt +  4) = *(const float4*)(wc +  4);
    *(float4*)(wt +  8) = *(const float4*)(wc +  8);
    *(float4*)(wt + 12) = *(const float4*)(wc + 12);
    float vv[16];
    #pragma unroll
    for (int pp = 0; pp < 4; ++pp)
      #pragma unroll
      for (int rr = 0; rr < 4; ++rr)
        vv[pp * 4 + rr] = p[pp*4+0]*wt[0+rr] + p[pp*4+1]*wt[4+rr]
                        + p[pp*4+2]*wt[8+rr] + p[pp*4+3]*wt[12+rr];
    H8U lo, hi;
    #pragma unroll
    for (int jj = 0; jj < 4; ++jj) {
      lo.q[jj] = pkrtz(vv[2*jj],     vv[2*jj + 1]);
      hi.q[jj] = pkrtz(vv[8 + 2*jj], vv[8 + 2*jj + 1]);
    }
    *(h8*)(sVh + i * VH_S)     = lo.v;
    *(h8*)(sVh + i * VH_S + 8) = hi.v;
  }
  __syncthreads();

  // ---- step 2: A^T[o][i] = exp(Vf[i].qf[o]/3) via MFMA 16x16x32 (K zero-padded) ----
  {
    const int lo16 = l & 15;
    const int q4   = l >> 4;          // k-quad
    const int kq   = (q4 & 1) * 8;    // real k base for quads 0,1
    const bool hiK = (q4 >= 2);       // quads 2,3 = zero-pad region (k>=16)
    h8 bf[2];
    #pragma unroll
    for (int nt = 0; nt < 2; ++nt) {
      const int o = lo16 + 16 * nt;
      H8U bu;
      #pragma unroll
      for (int jj = 0; jj < 4; ++jj)
        bu.q[jj] = pkrtz(sQt[(kq + 2*jj) * 32 + o], sQt[(kq + 2*jj + 1) * 32 + o]);
      bf[nt] = hiK ? zero8 : bu.v;
    }
    for (int mt = wv; mt < 18; mt += 4) {
      const int m = mt * 16 + lo16;
      h8 af = *(const h8*)(sVh + m * VH_S + kq);
      if (hiK) af = zero8;
      #pragma unroll
      for (int nt = 0; nt < 2; ++nt) {
        v4f acc = {0.f, 0.f, 0.f, 0.f};
        acc = __builtin_amdgcn_mfma_f32_16x16x32_f16(af, bf[nt], acc, 0, 0, 0);
        // D: col(o-within-tile)=l&15, row(i-offset)=4*q4+reg
        const int o  = lo16 + 16 * nt;
        const int ib = mt * 16 + 4 * q4;
        h2 p0 = pkrtz(__expf(acc[0]), __expf(acc[1]));
        h2 p1 = pkrtz(__expf(acc[2]), __expf(acc[3]));
        int2 wr; wr.x = h2bits(p0); wr.y = h2bits(p1);
        *(int2*)(sAt + o * AT_S + ib) = wr;   // A^T[o][ib..ib+3]
      }
    }
  }
  __syncthreads();

  // ---- step 3: Sinkhorn in registers, RESCALED (v-step = 8/colsum; exact x0.375 comp later).
  // All cross-lane reductions on the VALU via DPP -- zero ds_bpermute.
  const int c4 = t & 7;
  const int hq = t >> 3;
  h2 A2a[9], A2b[9];
  {
    const _Float16* r0 = sAt + (4*c4 + 0) * AT_S + 9 * hq;
    const _Float16* r1 = sAt + (4*c4 + 1) * AT_S + 9 * hq;
    const _Float16* r2 = sAt + (4*c4 + 2) * AT_S + 9 * hq;
    const _Float16* r3 = sAt + (4*c4 + 3) * AT_S + 9 * hq;
    #pragma unroll
    for (int j = 0; j < 9; ++j) {
      h2 a; a.x = r0[j]; a.y = r1[j]; A2a[j] = a;
      h2 c; c.x = r2[j]; c.y = r3[j]; A2b[j] = c;
    }
  }
  float ureg[9];
  for (int it = 0; it < ITERS; ++it) {
    const v4f vvv = *(const v4f*)(sU + NI + 4 * c4);
    const h2 v2a = pkrtz(vvv[0], vvv[1]);
    const h2 v2b = pkrtz(vvv[2], vvv[3]);
    // u-pass: row sums over o; reduce across the 8 c4-lanes via DPP (xor1,xor2,half-mirror)
    #pragma unroll
    for (int j = 0; j < 9; ++j) {
      float s = dot2f(A2b[j], v2b, dot2f(A2a[j], v2a, 0.f));
      s = dpp_add<DPP_XOR1>(s);
      s = dpp_add<DPP_XOR2>(s);
      s = dpp_add<DPP_HMIR>(s);
      ureg[j] = __builtin_amdgcn_rcpf(s);
    }
    // col-pass: fp32 partial col sums; ror:8 folds the two hq-chunks in each 16-row
    float sca = 0.f, scb = 0.f, scc = 0.f, scd = 0.f;
    #pragma unroll
    for (int j = 0; j < 9; ++j) {
      const float uj = ureg[j];
      sca += (float)A2a[j].x * uj;
      scb += (float)A2a[j].y * uj;
      scc += (float)A2b[j].x * uj;
      scd += (float)A2b[j].y * uj;
    }
    sca = dpp_add<DPP_ROR8>(sca);
    scb = dpp_add<DPP_ROR8>(scb);
    scc = dpp_add<DPP_ROR8>(scc);
    scd = dpp_add<DPP_ROR8>(scd);
    if ((l & 15) < 8) {
      v4f w4; w4[0] = sca; w4[1] = scb; w4[2] = scc; w4[3] = scd;
      *(v4f*)(sScr + (t >> 4) * 32 + (l & 7) * 4) = w4;   // [16-group][o]
    }
    __syncthreads();
    if (t < 32) {
      float S = 0.f;
      #pragma unroll
      for (int g = 0; g < 16; ++g) S += sScr[g * 32 + t];
      sU[NI + t] = 8.0f * __builtin_amdgcn_rcpf(S);   // rescaled v
    }
    __syncthreads();
  }
  if (c4 == 0) {
    #pragma unroll
    for (int j = 0; j < 9; ++j) sU[9 * hq + j] = ureg[j];
  }
  __syncthreads();

  // ---- step 5: np~[o][d] = sum_k A^T[o][k] * (u_k * V[k][d]) via MFMA 16x16x32 ----
  v4f acc5_0 = {0.f, 0.f, 0.f, 0.f};
  v4f acc5_1 = {0.f, 0.f, 0.f, 0.f};
  {
    const int d  = l & 15;
    const int q4 = l >> 4;
    for (int kt = wv; kt < 9; kt += 4) {
      const int kg = kt * 32 + q4 * 8;
      const v4f ua = *(const v4f*)(sU + kg);
      const v4f ub = *(const v4f*)(sU + kg + 4);
      float uu[8];
      #pragma unroll
      for (int z = 0; z < 4; ++z) { uu[z] = ua[z]; uu[4 + z] = ub[z]; }
      H8U bu;
      #pragma unroll
      for (int jj = 0; jj < 4; ++jj) {
        const float b0 = (float)sVh[(kg + 2*jj)     * VH_S + d] * uu[2*jj];
        const float b1 = (float)sVh[(kg + 2*jj + 1) * VH_S + d] * uu[2*jj + 1];
        bu.q[jj] = pkrtz(b0, b1);
      }
      const h8 af0 = *(const h8*)(sAt + d * AT_S        + kt * 32 + q4 * 8);
      const h8 af1 = *(const h8*)(sAt + (16 + d) * AT_S + kt * 32 + q4 * 8);
      acc5_0 = __builtin_amdgcn_mfma_f32_16x16x32_f16(af0, bu.v, acc5_0, 0, 0, 0);
      acc5_1 = __builtin_amdgcn_mfma_f32_16x16x32_f16(af1, bu.v, acc5_1, 0, 0, 0);
    }
  }
  __syncthreads();   // all sVh/sAt reads done -> safe to overlay P into sVh
  {
    const int d = l & 15, q4 = l >> 4;
    // D: col=d, row(o-offset)=4*q4+reg
    *(v4f*)(Pf + (wv * 16 + d) * P_S + 0  + 4 * q4) = acc5_0;
    *(v4f*)(Pf + (wv * 16 + d) * P_S + 16 + 4 * q4) = acc5_1;
  }
  __syncthreads();
  // combine K-partials; np*3 = S~ * v~_o * (3/8)  (the /8 undoes the v rescale)
  #pragma unroll
  for (int pass = 0; pass < 2; ++pass) {
    const int e = t + 256 * pass;
    const int o = e & 31, dd = e >> 5;
    const float S = Pf[(0 * 16 + dd) * P_S + o] + Pf[(1 * 16 + dd) * P_S + o]
                  + Pf[(2 * 16 + dd) * P_S + o] + Pf[(3 * 16 + dd) * P_S + o];
    sScr[dd * 32 + o] = S * 0.375f * sU[NI + o];
  }
  __syncthreads();

  // ---- step 6: out[o][p*4+r] = sum_q np[o][p*4+q]*w_next[o][q*4+r]; LayerNorm over d ----
  {
    float vals[2];
    #pragma unroll
    for (int h2p = 0; h2p < 2; ++h2p) {
      const int e = t + h2p * 256;
      const int o = e >> 4, dd = e & 15;
      const int pp = dd >> 2, rr = dd & 3;
      float acc = 0.f;
      #pragma unroll
      for (int q = 0; q < 4; ++q)
        acc += sScr[(pp * 4 + q) * 32 + o] * sQt[(q * 4 + rr) * 32 + o];
      vals[h2p] = acc;
    }
    // LN over the 16 d's: full-16 DPP reduction (quad sums, then rotate-4/8)
    float s0 = vals[0], q0 = vals[0] * vals[0];
    float s1 = vals[1], q1 = vals[1] * vals[1];
    s0 = dpp_add<DPP_XOR1>(s0); q0 = dpp_add<DPP_XOR1>(q0);
    s1 = dpp_add<DPP_XOR1>(s1); q1 = dpp_add<DPP_XOR1>(q1);
    s0 = dpp_add<DPP_XOR2>(s0); q0 = dpp_add<DPP_XOR2>(q0);
    s1 = dpp_add<DPP_XOR2>(s1); q1 = dpp_add<DPP_XOR2>(q1);
    s0 = dpp_add<DPP_ROR4>(s0); q0 = dpp_add<DPP_ROR4>(q0);
    s1 = dpp_add<DPP_ROR4>(s1); q1 = dpp_add<DPP_ROR4>(q1);
    s0 = dpp_add<DPP_ROR8>(s0); q0 = dpp_add<DPP_ROR8>(q0);
    s1 = dpp_add<DPP_ROR8>(s1); q1 = dpp_add<DPP_ROR8>(q1);
    #pragma unroll
    for (int h2p = 0; h2p < 2; ++h2p) {
      const int e = t + h2p * 256;
      const int o = e >> 4, dd = e & 15;
      const float ss = h2p ? s1 : s0;
      const float qq = h2p ? q1 : q0;
      const float mu   = ss * (1.0f / 16.0f);
      const float var  = qq * (1.0f / 16.0f) - mu * mu;
      const float rstd = rsqrtf(var + EPS);
      const float y = (vals[h2p] - mu) * rstd * ln_scale[dd] + ln_bias[dd];
      out[(((b * OUT_N + o) * HW + hh) * HW + ww) * D + dd] = y;
    }
  }
}

extern "C" void kernel_launch(void* const* d_in, const int* in_sizes, int n_in,
                              void* d_out, int out_size, void* d_ws, size_t ws_size,
                              hipStream_t stream) {
  const float* input     = (const float*)d_in[0];
  const float* w_current = (const float*)d_in[1];
  const float* w_next    = (const float*)d_in[2];
  const float* ln_scale  = (const float*)d_in[3];
  const float* ln_bias   = (const float*)d_in[4];
  float* outp = (float*)d_out;

  dim3 grid(BATCH * HW * HW);   // 2704 blocks, one per (b, h, w)
  dim3 block(256);
  capsule_fused<<<grid, block, 0, stream>>>(input, w_current, w_next,
                                            ln_scale, ln_bias, outp);
}